// Round 14
// baseline (39.993 us; speedup 1.0000x reference)
//
#include <hip/hip_runtime.h>
#include <math.h>

// st_VQEmbedding via MFMA, whole-codebook-in-LDS, barrier-free k-loop.
// z [65536,64] f32, emb [512,64] f32 -> out = emb[argmin_k (x2-2dot)+e2],
// straight-through (q+x)-x. dot via bf16 2-term split MFMA (al*bh + ah*bl +
// ah*bh, fp32 accum) -- bit-identical chains/term order to R5/R7/R8/R12/R13
// (all passed absmax 0.0).
//
// R14: R7-R13 all land ~37us across occupancy/ILP/VGPR/LDS-traffic changes.
// Per-pipe budget says ~9us overlapped, ~23us serial -> pipes never overlap:
// the per-chunk __syncthreads phase-locks all waves (everyone ds_reads, then
// everyone MFMAs, then everyone stalls on the same drain). Fix: stage the
// ENTIRE 128KB hi/lo image + e2 into LDS once (1 block/CU, 1024 thr), ONE
// barrier, then a zero-barrier k-loop where wave w visits code-tiles in
// rotated order (start tile 2w) -> waves drift across pipes. Rotated visit
// order => lexicographic (val,idx) argmin update (provably same first-index
// semantics; dist bit-values unchanged).

constexpr int K     = 512;
constexpr int D     = 64;
constexpr int NPTS  = 16 * 4096;   // 65536
constexpr int BLOCK = 1024;        // 16 waves
constexpr int PPB   = 256;         // points per block (16 waves x 16)
constexpr int NT    = K / 16;      // 32 code-tiles

typedef __attribute__((ext_vector_type(8))) short  short8;
typedef __attribute__((ext_vector_type(4))) float  f32x4;

#define AS_G (const __attribute__((address_space(1))) void*)
#define AS_L (__attribute__((address_space(3))) void*)

__device__ inline unsigned short bf16_rne(float f) {
    unsigned u = __builtin_bit_cast(unsigned, f);
    u += 0x7fffu + ((u >> 16) & 1u);
    return (unsigned short)(u >> 16);
}
__device__ inline float bf16_f32(unsigned short h) {
    unsigned u = (unsigned)h << 16;
    return __builtin_bit_cast(float, u);
}

// ---- prep: one thread per code. e2 (exact chain) + bf16 hi/lo split,
// LDS-image order: granule g = k*8 + (s ^ (k&7))  [R9/R10 prep, proven]. ----
__global__ void prep_emb(const float* __restrict__ emb,
                         float* __restrict__ e2,
                         short8* __restrict__ wsHi,
                         short8* __restrict__ wsLo)
{
    const int k = blockIdx.x * 128 + threadIdx.x;   // 4 blocks x 128 = 512
    const float4* row = reinterpret_cast<const float4*>(emb + k * D);
    float v[64];
    #pragma unroll
    for (int i = 0; i < 16; ++i) {
        float4 q = row[i];
        v[4*i+0] = q.x; v[4*i+1] = q.y; v[4*i+2] = q.z; v[4*i+3] = q.w;
    }
    float acc = 0.0f;
    {
        #pragma clang fp contract(off)
        #pragma unroll
        for (int d = 0; d < 64; ++d) acc = acc + v[d] * v[d];
    }
    e2[k] = acc;
    #pragma unroll
    for (int s = 0; s < 8; ++s) {
        short8 hi, lo;
        #pragma unroll
        for (int e = 0; e < 8; ++e) {
            const float f = v[s * 8 + e];
            const unsigned short h = bf16_rne(f);
            const float r = f - bf16_f32(h);      // exact (Sterbenz)
            hi[e] = (short)h;
            lo[e] = (short)bf16_rne(r);
        }
        const int g = k * 8 + (s ^ (k & 7));
        wsHi[g] = hi;
        wsLo[g] = lo;
    }
}

// ---- main: codebook fully LDS-resident, barrier-free rotated k-loop -------
__global__ __launch_bounds__(BLOCK, 1)
void vq_mfma(const float* __restrict__ z,
             const float* __restrict__ emb,
             const float* __restrict__ e2,
             const short8* __restrict__ wsHi,
             const short8* __restrict__ wsLo,
             float* __restrict__ out)
{
    __shared__ short8 Ahi[4096];      // 64 KiB (whole codebook hi)
    __shared__ short8 Alo[4096];      // 64 KiB (whole codebook lo)
    __shared__ float4 e2L[K / 4];     // 2 KiB
    __shared__ int    bidx_s[PPB];    // 1 KiB

    const int tid = threadIdx.x;
    const int w   = tid >> 6;         // wave 0..15 -> owns point-tile w
    const int l   = tid & 63;
    const int col = l & 15;           // point within tile / code within tile
    const int kg  = l >> 4;           // k-group / code-row group

    const float4* zf4 = reinterpret_cast<const float4*>(z);
    const float4* ef4 = reinterpret_cast<const float4*>(emb);
    float4*       of4 = reinterpret_cast<float4*>(out);

    const int base = blockIdx.x * PPB;
    const int pt   = base + w * 16 + col;   // this lane's point

    // ---- stage entire image: 4 gloads per thread per array, lane-linear ----
    #pragma unroll
    for (int i = 0; i < 4; ++i) {
        const int g = i * BLOCK + tid;
        __builtin_amdgcn_global_load_lds(AS_G(wsHi + g), AS_L(&Ahi[g]), 16, 0, 0);
        __builtin_amdgcn_global_load_lds(AS_G(wsLo + g), AS_L(&Alo[g]), 16, 0, 0);
    }
    if (tid < K / 4)
        __builtin_amdgcn_global_load_lds(AS_G(e2 + tid * 4), AS_L(&e2L[tid]), 16, 0, 0);

    // ---- x2 for this lane's point, exact sequential unfused chain ----
    float x2v = 0.0f;
    {
        #pragma clang fp contract(off)
        #pragma unroll
        for (int i = 0; i < 16; ++i) {
            float4 q = zf4[pt * 16 + i];
            x2v = x2v + q.x * q.x;
            x2v = x2v + q.y * q.y;
            x2v = x2v + q.z * q.z;
            x2v = x2v + q.w * q.w;
        }
    }

    // ---- B-frags for this wave's point-tile (identical build to R12/R13) ----
    short8 bh[2], bl[2];
    #pragma unroll
    for (int kt = 0; kt < 2; ++kt) {
        const float4 va = zf4[pt * 16 + kt * 8 + kg * 2];
        const float4 vb = zf4[pt * 16 + kt * 8 + kg * 2 + 1];
        const float xs[8] = {va.x, va.y, va.z, va.w, vb.x, vb.y, vb.z, vb.w};
        #pragma unroll
        for (int e = 0; e < 8; ++e) {
            const unsigned short h = bf16_rne(xs[e]);
            const float r = xs[e] - bf16_f32(h);   // exact
            bh[kt][e] = (short)h;
            bl[kt][e] = (short)bf16_rne(r);
        }
    }

    __syncthreads();   // the ONLY pre-epilogue barrier: image + e2L resident

    float best = INFINITY;
    int   bi   = 0x7fffffff;

    // rotated visit order: wave w starts at tile 2w -> waves de-phase
    for (int i = 0; i < NT; ++i) {
        const int tt = (w * 2 + i) & (NT - 1);

        // swizzled slots: code = tt*16+col, sidx = (kt*4+kg)^(col&7)
        const int slot0 = ((tt * 16 + col) << 3) | (kg ^ (col & 7)); // kt=0
        const short8 ah0 = Ahi[slot0];
        const short8 ah1 = Ahi[slot0 ^ 4];                            // kt=1
        const short8 al0 = Alo[slot0];
        const short8 al1 = Alo[slot0 ^ 4];

        f32x4 acc = {0.f, 0.f, 0.f, 0.f};
        // same term order as R5/R7/R8/R12/R13: per kt {al*bh, ah*bl, ah*bh}
        acc = __builtin_amdgcn_mfma_f32_16x16x32_bf16(al0, bh[0], acc, 0, 0, 0);
        acc = __builtin_amdgcn_mfma_f32_16x16x32_bf16(ah0, bl[0], acc, 0, 0, 0);
        acc = __builtin_amdgcn_mfma_f32_16x16x32_bf16(ah0, bh[0], acc, 0, 0, 0);
        acc = __builtin_amdgcn_mfma_f32_16x16x32_bf16(al1, bh[1], acc, 0, 0, 0);
        acc = __builtin_amdgcn_mfma_f32_16x16x32_bf16(ah1, bl[1], acc, 0, 0, 0);
        acc = __builtin_amdgcn_mfma_f32_16x16x32_bf16(ah1, bh[1], acc, 0, 0, 0);

        const int   kbase = tt * 16 + kg * 4;
        const float4 e2v  = e2L[kbase >> 2];   // broadcast-pattern ds_read
        const float d0 = (x2v - 2.0f * acc[0]) + e2v.x;
        const float d1 = (x2v - 2.0f * acc[1]) + e2v.y;
        const float d2 = (x2v - 2.0f * acc[2]) + e2v.z;
        const float d3 = (x2v - 2.0f * acc[3]) + e2v.w;

        // tree argmin within tile (ascending k; ties -> lower k) ...
        float mv01 = d0; int mi01 = kbase + 0;
        if (d1 < mv01) { mv01 = d1; mi01 = kbase + 1; }
        float mv23 = d2; int mi23 = kbase + 2;
        if (d3 < mv23) { mv23 = d3; mi23 = kbase + 3; }
        float mv = mv01; int mi = mi01;
        if (mv23 < mv) { mv = mv23; mi = mi23; }
        // ... then LEX update vs running best (visit order is rotated, so
        // the tie clause restores global first-index semantics exactly).
        if (mv < best || (mv == best && mi < bi)) { best = mv; bi = mi; }
    }

    // combine 4 kg-groups (lanes sharing a column): lexicographic (dist, idx)
    #pragma unroll
    for (int off = 16; off < 64; off <<= 1) {
        const float ov = __shfl_xor(best, off);
        const int   oi = __shfl_xor(bi,   off);
        if (ov < best || (ov == best && oi < bi)) { best = ov; bi = oi; }
    }
    if (l < 16) bidx_s[w * 16 + col] = bi;
    __syncthreads();

    // dense epilogue: lane-linear float4 stores, straight-through (q+x)-x
    #pragma unroll
    for (int i = 0; i < (PPB * 16) / BLOCK; ++i) {   // 4 iters
        const int idx = i * BLOCK + tid;
        const int p   = idx >> 4;
        const int j   = idx & 15;
        const float4 q = ef4[bidx_s[p] * 16 + j];
        const float4 x = zf4[(base + p) * 16 + j];
        float4 o;
        o.x = (q.x + x.x) - x.x;
        o.y = (q.y + x.y) - x.y;
        o.z = (q.z + x.z) - x.z;
        o.w = (q.w + x.w) - x.w;
        of4[(base + p) * 16 + j] = o;
    }
}

extern "C" void kernel_launch(void* const* d_in, const int* in_sizes, int n_in,
                              void* d_out, int out_size, void* d_ws, size_t ws_size,
                              hipStream_t stream) {
    const float* z   = (const float*)d_in[0];
    const float* emb = (const float*)d_in[1];
    float* out = (float*)d_out;

    // ws: e2 f32[512] (2KB) | wsHi short8[4096] (64KB) | wsLo short8[4096] (64KB)
    float*  e2   = (float*)d_ws;
    short8* wsHi = (short8*)((char*)d_ws + 2048);
    short8* wsLo = (short8*)((char*)d_ws + 2048 + 65536);

    prep_emb<<<4, 128, 0, stream>>>(emb, e2, wsHi, wsLo);
    vq_mfma<<<NPTS / PPB, BLOCK, 0, stream>>>(z, emb, e2, wsHi, wsLo, out);
}